// Round 1
// baseline (1493.882 us; speedup 1.0000x reference)
//
#include <hip/hip_runtime.h>

typedef __attribute__((ext_vector_type(8))) short short8;
typedef __attribute__((ext_vector_type(4))) float f32x4;

#define MFMA(a,b,c) __builtin_amdgcn_mfma_f32_16x16x32_bf16(a,b,c,0,0,0)

constexpr int NT  = 49;     // tokens per window
constexpr int CD  = 384;    // channels
constexpr int NH  = 12;     // heads
constexpr int BW  = 1024;   // windows
constexpr float ATT_SCALE = 0.17677669529663687f;  // 32^-0.5

__device__ __forceinline__ unsigned short f2bf(float f) {
  union { float f; unsigned u; } v; v.f = f;
  return (unsigned short)((v.u + 0x8000u) >> 16);   // round-half-up to bf16
}

__device__ __forceinline__ short8 ld8f(const float* p) {
  float4 a = *(const float4*)p;
  float4 b = *(const float4*)(p + 4);
  short8 r;
  r[0]=(short)f2bf(a.x); r[1]=(short)f2bf(a.y); r[2]=(short)f2bf(a.z); r[3]=(short)f2bf(a.w);
  r[4]=(short)f2bf(b.x); r[5]=(short)f2bf(b.y); r[6]=(short)f2bf(b.z); r[7]=(short)f2bf(b.w);
  return r;
}

// ---------------- prologue: transpose weights to bf16 [n][k] ----------------
__global__ void k_wtrans(const float* __restrict__ W, unsigned short* __restrict__ Wt,
                         int K, int N) {
  int t = blockIdx.x * 256 + threadIdx.x;
  int total = N * (K / 8);
  if (t >= total) return;
  int n = t % N, kg = t / N;
  int k0 = kg * 8;
  short8 r;
  #pragma unroll
  for (int e = 0; e < 8; ++e) r[e] = (short)f2bf(W[(long)(k0 + e) * N + n]);
  *(short8*)(Wt + (long)n * K + k0) = r;
}

// ---------------- prologue: rpb gather + mask combine ----------------
// comb[w][h][i][j] = rpb_table[rel(i,j)*12+h] + mask[w][i][j]
__global__ void k_comb(const float* __restrict__ rpb, const float* __restrict__ mask,
                       float* __restrict__ comb) {
  int t = blockIdx.x * 256 + threadIdx.x;
  if (t >= 16 * NH * NT * NT) return;
  int wh = t / (NT * NT), ij = t % (NT * NT);
  int w = wh / NH, h = wh % NH;
  int i = ij / NT, j = ij % NT;
  int yi = i / 7, xi = i - 7 * yi, yj = j / 7, xj = j - 7 * yj;
  int rel = (yi - yj + 6) * 13 + (xi - xj + 6);
  comb[t] = rpb[rel * NH + h] + mask[(long)w * NT * NT + ij];
}

// ---------------- fused attention: one block per (window, head) ----------------
__global__ __launch_bounds__(256) void k_attn(
    const float* __restrict__ X, const float* __restrict__ SC, const float* __restrict__ SH,
    const unsigned short* __restrict__ WqkvT,
    const unsigned short* __restrict__ WvsT,
    const unsigned short* __restrict__ WvhT,
    const float* __restrict__ qkvb, const float* __restrict__ vsb, const float* __restrict__ vhb,
    const float* __restrict__ comb,
    unsigned short* __restrict__ O)   // [3][BW*NT][CD] bf16
{
  int lid = blockIdx.x;
  int wg = (lid & 7) * 1536 + (lid >> 3);   // XCD swizzle: same-window heads -> same XCD
  int b = wg / NH, h = wg % NH;

  const int tid = threadIdx.x;
  const int w = tid >> 6;          // wave = m-tile (rows w*16..w*16+15)
  const int lane = tid & 63;
  const int lr = lane & 15;
  const int lg = lane >> 4;

  __shared__ __align__(16) unsigned short Qs[64 * 40];       // [row][d], stride 40
  __shared__ __align__(16) unsigned short Ks[64 * 40];
  __shared__ __align__(16) unsigned short Ps[64 * 64];       // [i][j], XOR-swizzled
  __shared__ __align__(16) unsigned short VT[3][32 * 64];    // [d][j], XOR-swizzled

  // ---------- phase A: Q,K,V,Vs,Vh projections ----------
  const int rtok = w * 16 + lr;
  const int rc = rtok < NT ? rtok : NT - 1;   // clamp OOB rows (garbage rows masked later)
  const float* xp = X  + ((long)b * NT + rc) * CD + lg * 8;
  const float* sp = SC + ((long)b * NT + rc) * CD + lg * 8;
  const float* tp = SH + ((long)b * NT + rc) * CD + lg * 8;

  const int nc0 = h * 32 + lr;
  const unsigned short* pq0 = WqkvT + (long)(nc0)        * CD + lg * 8;
  const unsigned short* pq1 = WqkvT + (long)(nc0 + 16)   * CD + lg * 8;
  const unsigned short* pk0 = WqkvT + (long)(384 + nc0)  * CD + lg * 8;
  const unsigned short* pk1 = WqkvT + (long)(400 + nc0)  * CD + lg * 8;
  const unsigned short* pv0 = WqkvT + (long)(768 + nc0)  * CD + lg * 8;
  const unsigned short* pv1 = WqkvT + (long)(784 + nc0)  * CD + lg * 8;
  const unsigned short* ps0 = WvsT + (long)(nc0)      * CD + lg * 8;
  const unsigned short* ps1 = WvsT + (long)(nc0 + 16) * CD + lg * 8;
  const unsigned short* ph0 = WvhT + (long)(nc0)      * CD + lg * 8;
  const unsigned short* ph1 = WvhT + (long)(nc0 + 16) * CD + lg * 8;

  f32x4 aq0,aq1,ak0,ak1,av0,av1,cs0,cs1,ch0,ch1;
  aq0=aq1=ak0=ak1=av0=av1=cs0=cs1=ch0=ch1=(f32x4){0.f,0.f,0.f,0.f};

  #pragma unroll
  for (int kk = 0; kk < 12; ++kk) {
    short8 ax = ld8f(xp + kk * 32);
    short8 asv = ld8f(sp + kk * 32);
    short8 atv = ld8f(tp + kk * 32);
    short8 b0, b1;
    b0 = *(const short8*)(pq0 + kk * 32); b1 = *(const short8*)(pq1 + kk * 32);
    aq0 = MFMA(ax, b0, aq0); aq1 = MFMA(ax, b1, aq1);
    b0 = *(const short8*)(pk0 + kk * 32); b1 = *(const short8*)(pk1 + kk * 32);
    ak0 = MFMA(ax, b0, ak0); ak1 = MFMA(ax, b1, ak1);
    b0 = *(const short8*)(pv0 + kk * 32); b1 = *(const short8*)(pv1 + kk * 32);
    av0 = MFMA(ax, b0, av0); av1 = MFMA(ax, b1, av1);
    b0 = *(const short8*)(ps0 + kk * 32); b1 = *(const short8*)(ps1 + kk * 32);
    cs0 = MFMA(asv, b0, cs0); cs1 = MFMA(asv, b1, cs1);
    b0 = *(const short8*)(ph0 + kk * 32); b1 = *(const short8*)(ph1 + kk * 32);
    ch0 = MFMA(atv, b0, ch0); ch1 = MFMA(atv, b1, ch1);
  }

  float bq_0 = qkvb[nc0],       bq_1 = qkvb[nc0 + 16];
  float bk_0 = qkvb[384 + nc0], bk_1 = qkvb[400 + nc0];
  float bv_0 = qkvb[768 + nc0], bv_1 = qkvb[784 + nc0];
  float bs_0 = vsb[nc0],        bs_1 = vsb[nc0 + 16];
  float bh_0 = vhb[nc0],        bh_1 = vhb[nc0 + 16];

  // scatter D-frags (row=(lg*4+q), col=lr per 16x16 tile) to LDS
  #pragma unroll
  for (int q = 0; q < 4; ++q) {
    int r = w * 16 + lg * 4 + q;
    if (r < NT) {
      {
        int d = lr;
        Qs[r * 40 + d] = f2bf(aq0[q] + bq_0);
        Ks[r * 40 + d] = f2bf(ak0[q] + bk_0);
        int by = d * 128 + ((2 * r) ^ ((d & 7) << 4));
        *(unsigned short*)((char*)VT[0] + by) = f2bf(av0[q] + bv_0);
        *(unsigned short*)((char*)VT[1] + by) = f2bf(cs0[q] + bs_0);
        *(unsigned short*)((char*)VT[2] + by) = f2bf(ch0[q] + bh_0);
      }
      {
        int d = lr + 16;
        Qs[r * 40 + d] = f2bf(aq1[q] + bq_1);
        Ks[r * 40 + d] = f2bf(ak1[q] + bk_1);
        int by = d * 128 + ((2 * r) ^ ((d & 7) << 4));
        *(unsigned short*)((char*)VT[0] + by) = f2bf(av1[q] + bv_1);
        *(unsigned short*)((char*)VT[1] + by) = f2bf(cs1[q] + bs_1);
        *(unsigned short*)((char*)VT[2] + by) = f2bf(ch1[q] + bh_1);
      }
    }
  }
  // zero-fill V^T K-pad columns j in [49,64) so P(=0) * V(=0) is exact
  for (int idx = tid; idx < 3 * 32 * 15; idx += 256) {
    int s = idx / 480, rem = idx % 480;
    int d = rem / 15, j = 49 + rem % 15;
    int by = d * 128 + ((2 * j) ^ ((d & 7) << 4));
    *(unsigned short*)((char*)VT[s] + by) = 0;
  }
  __syncthreads();

  // ---------- phase B: QK^T + softmax -> Ps ----------
  short8 aQ = *(const short8*)(Qs + (w * 16 + lr) * 40 + lg * 8);
  f32x4 z4 = {0.f,0.f,0.f,0.f};
  f32x4 s0 = MFMA(aQ, *(const short8*)(Ks + (0 * 16 + lr) * 40 + lg * 8), z4);
  f32x4 s1 = MFMA(aQ, *(const short8*)(Ks + (1 * 16 + lr) * 40 + lg * 8), z4);
  f32x4 s2 = MFMA(aQ, *(const short8*)(Ks + (2 * 16 + lr) * 40 + lg * 8), z4);
  f32x4 s3 = MFMA(aQ, *(const short8*)(Ks + (3 * 16 + lr) * 40 + lg * 8), z4);

  const float* chp = comb + (long)((b & 15) * NH + h) * (NT * NT);
  #pragma unroll
  for (int q = 0; q < 4; ++q) {
    int i = w * 16 + lg * 4 + q;
    bool rowok = i < NT;
    const float* chi = chp + i * NT;
    float t0 = rowok ? s0[q] * ATT_SCALE + chi[lr]      : -1e30f;
    float t1 = rowok ? s1[q] * ATT_SCALE + chi[16 + lr] : -1e30f;
    float t2 = rowok ? s2[q] * ATT_SCALE + chi[32 + lr] : -1e30f;
    float t3 = (rowok && lr == 0) ? s3[q] * ATT_SCALE + chi[48] : -1e30f;
    float mx = fmaxf(fmaxf(t0, t1), fmaxf(t2, t3));
    #pragma unroll
    for (int d = 1; d < 16; d <<= 1) mx = fmaxf(mx, __shfl_xor(mx, d));
    float e0 = __expf(t0 - mx), e1 = __expf(t1 - mx);
    float e2 = __expf(t2 - mx), e3 = __expf(t3 - mx);
    float sm = e0 + e1 + e2 + e3;
    #pragma unroll
    for (int d = 1; d < 16; d <<= 1) sm += __shfl_xor(sm, d);
    float inv = 1.0f / sm;
    if (rowok) {
      int byb = i * 128, sw = (i & 7) << 4;
      *(unsigned short*)((char*)Ps + byb + ((2 * (lr))      ^ sw)) = f2bf(e0 * inv);
      *(unsigned short*)((char*)Ps + byb + ((2 * (16 + lr)) ^ sw)) = f2bf(e1 * inv);
      *(unsigned short*)((char*)Ps + byb + ((2 * (32 + lr)) ^ sw)) = f2bf(e2 * inv);
      *(unsigned short*)((char*)Ps + byb + ((2 * (48 + lr)) ^ sw)) = f2bf(e3 * inv);
    }
  }
  __syncthreads();

  // ---------- phase C: P @ V for 3 streams ----------
  int pr = w * 16 + lr;
  int psw = (pr & 7) << 4;
  short8 aP0 = *(const short8*)((const char*)Ps + pr * 128 + ((2 * (lg * 8))      ^ psw));
  short8 aP1 = *(const short8*)((const char*)Ps + pr * 128 + ((2 * (32 + lg * 8)) ^ psw));

  #pragma unroll
  for (int s = 0; s < 3; ++s) {
    unsigned short* Ob = O + (long)s * BW * NT * CD + (long)b * NT * CD + h * 32;
    #pragma unroll
    for (int n = 0; n < 2; ++n) {
      int d = n * 16 + lr;
      int vsw = (d & 7) << 4;
      const char* vb = (const char*)VT[s] + d * 128;
      short8 bv0 = *(const short8*)(vb + ((2 * (lg * 8))      ^ vsw));
      short8 bv1 = *(const short8*)(vb + ((2 * (32 + lg * 8)) ^ vsw));
      f32x4 o = MFMA(aP0, bv0, z4);
      o = MFMA(aP1, bv1, o);
      #pragma unroll
      for (int q = 0; q < 4; ++q) {
        int i = w * 16 + lg * 4 + q;
        if (i < NT) Ob[(long)i * CD + d] = f2bf(o[q]);
      }
    }
  }
}

// ---------------- output projection GEMM: M=50176, N=384, K=384 ----------------
__global__ __launch_bounds__(256) void k_proj(
    const unsigned short* __restrict__ A,   // [50176][384] bf16
    const unsigned short* __restrict__ Wt,  // [384 n][384 k] bf16
    const float* __restrict__ bias,
    float* __restrict__ out)
{
  int bm = blockIdx.x, bn = blockIdx.y;
  int tid = threadIdx.x, wid = tid >> 6, lane = tid & 63;
  int lr = lane & 15, lg = lane >> 4;
  int wm = wid >> 1, wn = wid & 1;
  long rowA0 = (long)bm * 128 + wm * 64;
  int  coln0 = bn * 128 + wn * 64;

  const unsigned short* Ap[4];
  const unsigned short* Bp[4];
  #pragma unroll
  for (int i = 0; i < 4; ++i) {
    Ap[i] = A  + (rowA0 + i * 16 + lr) * CD + lg * 8;
    Bp[i] = Wt + (long)(coln0 + i * 16 + lr) * CD + lg * 8;
  }

  f32x4 acc[4][4];
  #pragma unroll
  for (int i = 0; i < 4; ++i)
    #pragma unroll
    for (int j = 0; j < 4; ++j) acc[i][j] = (f32x4){0.f,0.f,0.f,0.f};

  for (int kk = 0; kk < 12; ++kk) {
    short8 a[4], bb[4];
    #pragma unroll
    for (int i = 0; i < 4; ++i) a[i]  = *(const short8*)(Ap[i] + kk * 32);
    #pragma unroll
    for (int i = 0; i < 4; ++i) bb[i] = *(const short8*)(Bp[i] + kk * 32);
    #pragma unroll
    for (int mf = 0; mf < 4; ++mf)
      #pragma unroll
      for (int nf = 0; nf < 4; ++nf)
        acc[mf][nf] = MFMA(a[mf], bb[nf], acc[mf][nf]);
  }

  #pragma unroll
  for (int nf = 0; nf < 4; ++nf) {
    int col = coln0 + nf * 16 + lr;
    float bv = bias[col];
    #pragma unroll
    for (int mf = 0; mf < 4; ++mf) {
      long row = rowA0 + mf * 16 + lg * 4;
      #pragma unroll
      for (int q = 0; q < 4; ++q)
        out[(row + q) * CD + col] = acc[mf][nf][q] + bv;
    }
  }
}

// ---------------- launch ----------------
extern "C" void kernel_launch(void* const* d_in, const int* in_sizes, int n_in,
                              void* d_out, int out_size, void* d_ws, size_t ws_size,
                              hipStream_t stream) {
  const float* x        = (const float*)d_in[0];
  const float* scale    = (const float*)d_in[1];
  const float* shift    = (const float*)d_in[2];
  const float* mask     = (const float*)d_in[3];
  const float* qkv_w    = (const float*)d_in[4];
  const float* qkv_b    = (const float*)d_in[5];
  const float* vscale_w = (const float*)d_in[6];
  const float* vscale_b = (const float*)d_in[7];
  const float* vshift_w = (const float*)d_in[8];
  const float* vshift_b = (const float*)d_in[9];
  const float* rpb      = (const float*)d_in[10];
  const float* proj_x_w = (const float*)d_in[11];
  const float* proj_x_b = (const float*)d_in[12];
  const float* proj_s_w = (const float*)d_in[13];
  const float* proj_s_b = (const float*)d_in[14];
  const float* proj_h_w = (const float*)d_in[15];
  const float* proj_h_b = (const float*)d_in[16];

  // workspace carve-up (all 16B aligned)
  unsigned short* wsO   = (unsigned short*)d_ws;        // 3 * 50176 * 384 bf16
  unsigned short* wqkvT = wsO + (size_t)3 * BW * NT * CD;
  unsigned short* wvsT  = wqkvT + 1152 * 384;
  unsigned short* wvhT  = wvsT + 384 * 384;
  unsigned short* wpxT  = wvhT + 384 * 384;
  unsigned short* wpsT  = wpxT + 384 * 384;
  unsigned short* wphT  = wpsT + 384 * 384;
  float* comb           = (float*)(wphT + 384 * 384);   // 16*12*49*49 f32

  k_wtrans<<<216, 256, 0, stream>>>(qkv_w,    wqkvT, 384, 1152);
  k_wtrans<<<72,  256, 0, stream>>>(vscale_w, wvsT,  384, 384);
  k_wtrans<<<72,  256, 0, stream>>>(vshift_w, wvhT,  384, 384);
  k_wtrans<<<72,  256, 0, stream>>>(proj_x_w, wpxT,  384, 384);
  k_wtrans<<<72,  256, 0, stream>>>(proj_s_w, wpsT,  384, 384);
  k_wtrans<<<72,  256, 0, stream>>>(proj_h_w, wphT,  384, 384);
  k_comb<<<1801, 256, 0, stream>>>(rpb, mask, comb);

  k_attn<<<BW * NH, 256, 0, stream>>>(x, scale, shift, wqkvT, wvsT, wvhT,
                                      qkv_b, vscale_b, vshift_b, comb, wsO);

  dim3 g2(392, 3);
  float* out = (float*)d_out;
  const size_t ostride = (size_t)BW * NT * CD;
  k_proj<<<g2, 256, 0, stream>>>(wsO,               wpxT, proj_x_b, out);
  k_proj<<<g2, 256, 0, stream>>>(wsO + ostride,     wpsT, proj_s_b, out + ostride);
  k_proj<<<g2, 256, 0, stream>>>(wsO + 2 * ostride, wphT, proj_h_b, out + 2 * ostride);
}